// Round 1
// baseline (622.180 us; speedup 1.0000x reference)
//
#include <hip/hip_runtime.h>
#include <hip/hip_bf16.h>

#define TT 2048
#define CC 2048
#define HH 16
#define HS 128
#define BB 2
#define MM (BB*TT)   // 4096

typedef __attribute__((ext_vector_type(8))) short bf16x8;
typedef __attribute__((ext_vector_type(4))) short bf16x4;
typedef __attribute__((ext_vector_type(4))) float f32x4;

__device__ __forceinline__ short f2bf(float x) {
    unsigned u = __float_as_uint(x);
    unsigned r = (u + 0x7FFFu + ((u >> 16) & 1u)) >> 16;
    return (short)r;
}

// ---------------- fp32 -> bf16 convert (idx) ----------------
__global__ void cvt_bf16_kernel(const float* __restrict__ x, short* __restrict__ y, int n) {
    int stride = gridDim.x * blockDim.x;
    for (int i = blockIdx.x * blockDim.x + threadIdx.x; i < n/4; i += stride) {
        float4 v = reinterpret_cast<const float4*>(x)[i];
        bf16x4 s;
        s[0] = f2bf(v.x); s[1] = f2bf(v.y); s[2] = f2bf(v.z); s[3] = f2bf(v.w);
        reinterpret_cast<bf16x4*>(y)[i] = s;
    }
}

// ---------------- W [k][n] fp32  ->  Wt [n][k] bf16 ----------------
__global__ void wt_kernel(const float* __restrict__ w0, const float* __restrict__ w1,
                          const float* __restrict__ w2, const float* __restrict__ w3,
                          short* __restrict__ o0, short* __restrict__ o1,
                          short* __restrict__ o2, short* __restrict__ o3)
{
    const float* W; short* Wt;
    switch (blockIdx.z) {
        case 0:  W = w0; Wt = o0; break;
        case 1:  W = w1; Wt = o1; break;
        case 2:  W = w2; Wt = o2; break;
        default: W = w3; Wt = o3; break;
    }
    __shared__ float tile[32][33];
    int tx = threadIdx.x, ty = threadIdx.y;           // block (32,8)
    int k0 = blockIdx.x * 32, n0 = blockIdx.y * 32;
    #pragma unroll
    for (int i = 0; i < 4; ++i)
        tile[ty + i*8][tx] = W[(size_t)(k0 + ty + i*8) * CC + n0 + tx];
    __syncthreads();
    #pragma unroll
    for (int i = 0; i < 4; ++i)
        Wt[(size_t)(n0 + ty + i*8) * CC + k0 + tx] = f2bf(tile[tx][ty + i*8]);
}

// ---------------- GEMM: C[M][N] = A[M][K] * Bt[N][K]^T (+bias, *scale) ----------------
// MODE 0: dst = bf16 [B,H,T,hs] (QKV);  MODE 1: dst = fp32 [M][N]
template<int MODE>
__launch_bounds__(256)
__global__ void gemm_bt_kernel(const short* __restrict__ A, const short* __restrict__ Bt,
                               const float* __restrict__ bias, void* __restrict__ dst,
                               float scale)
{
    __shared__ __align__(16) short As[128*64];
    __shared__ __align__(16) short Bs[128*64];
    const int tid = threadIdx.x;
    const int lane = tid & 63;
    const int g = lane >> 4, fr = lane & 15;
    const int wid = tid >> 6;
    const int wr = wid >> 1, wc = wid & 1;
    const int m0 = blockIdx.x * 128, n0 = blockIdx.y * 128;

    f32x4 acc[4][4];
    #pragma unroll
    for (int i = 0; i < 4; ++i)
        #pragma unroll
        for (int j = 0; j < 4; ++j) acc[i][j] = (f32x4){0.f,0.f,0.f,0.f};

    for (int k0 = 0; k0 < CC; k0 += 64) {
        __syncthreads();
        // stage A tile [128 rows][64 k] bf16, XOR-swizzled (source-side permute)
        #pragma unroll
        for (int i = 0; i < 4; ++i) {
            int c = i*256 + tid;
            int row = c >> 3;
            int kb  = (c & 7) * 16;                 // physical kbyte in LDS row (128B rows)
            int kbl = kb ^ ((row & 7) << 4);        // logical kbyte in global
            const bf16x8* src = reinterpret_cast<const bf16x8*>(
                reinterpret_cast<const char*>(A) + ((size_t)(m0+row)*CC + k0)*2 + kbl);
            *reinterpret_cast<bf16x8*>(reinterpret_cast<char*>(As) + row*128 + kb) = *src;
        }
        // stage B tile
        #pragma unroll
        for (int i = 0; i < 4; ++i) {
            int c = i*256 + tid;
            int row = c >> 3;
            int kb  = (c & 7) * 16;
            int kbl = kb ^ ((row & 7) << 4);
            const bf16x8* src = reinterpret_cast<const bf16x8*>(
                reinterpret_cast<const char*>(Bt) + ((size_t)(n0+row)*CC + k0)*2 + kbl);
            *reinterpret_cast<bf16x8*>(reinterpret_cast<char*>(Bs) + row*128 + kb) = *src;
        }
        __syncthreads();
        #pragma unroll
        for (int cch = 0; cch < 2; ++cch) {
            bf16x8 a[4], b[4];
            #pragma unroll
            for (int i = 0; i < 4; ++i) {
                int row = wr*64 + i*16 + fr;
                int kb  = cch*64 + g*16;
                int kph = kb ^ ((row & 7) << 4);
                a[i] = *reinterpret_cast<const bf16x8*>(
                    reinterpret_cast<const char*>(As) + row*128 + kph);
            }
            #pragma unroll
            for (int j = 0; j < 4; ++j) {
                int row = wc*64 + j*16 + fr;
                int kb  = cch*64 + g*16;
                int kph = kb ^ ((row & 7) << 4);
                b[j] = *reinterpret_cast<const bf16x8*>(
                    reinterpret_cast<const char*>(Bs) + row*128 + kph);
            }
            #pragma unroll
            for (int i = 0; i < 4; ++i)
                #pragma unroll
                for (int j = 0; j < 4; ++j)
                    acc[i][j] = __builtin_amdgcn_mfma_f32_16x16x32_bf16(a[i], b[j], acc[i][j], 0, 0, 0);
        }
    }

    // epilogue: C/D layout col=lane&15, row=(lane>>4)*4+reg
    #pragma unroll
    for (int j = 0; j < 4; ++j) {
        int n = n0 + wc*64 + j*16 + fr;
        float bv = bias[n];
        #pragma unroll
        for (int i = 0; i < 4; ++i) {
            #pragma unroll
            for (int r = 0; r < 4; ++r) {
                int m = m0 + wr*64 + i*16 + g*4 + r;
                float val = (acc[i][j][r] + bv) * scale;
                if (MODE == 0) {
                    int bb = m >> 11, t = m & (TT-1);
                    int h  = n >> 7,  d = n & (HS-1);
                    reinterpret_cast<short*>(dst)[((size_t)(bb*HH + h)*TT + t)*HS + d] = f2bf(val);
                } else {
                    reinterpret_cast<float*>(dst)[(size_t)m*CC + n] = val;
                }
            }
        }
    }
}

// ---------------- causal flash attention ----------------
// grid (T/64, B*H), block 256: wave w owns q rows [bx*64 + w*16, +16)
__launch_bounds__(256)
__global__ void attn_kernel(const short* __restrict__ Q, const short* __restrict__ K,
                            const short* __restrict__ V, short* __restrict__ O)
{
    const int tid = threadIdx.x;
    const int lane = tid & 63;
    const int wid = tid >> 6;
    const int g = lane >> 4, fr = lane & 15;
    const int bh = blockIdx.y;
    const int q0 = blockIdx.x * 64 + wid * 16;
    const short* Qh = Q + (size_t)bh * TT * HS;
    const short* Kh = K + (size_t)bh * TT * HS;
    const short* Vh = V + (size_t)bh * TT * HS;

    __shared__ __align__(16) short plds[4][16*32];
    short* pl = plds[wid];

    // Q fragments (Q was pre-scaled by 1/sqrt(hs) in the QKV GEMM epilogue)
    bf16x8 qf[4];
    {
        int qrow = q0 + fr;
        #pragma unroll
        for (int c2 = 0; c2 < 4; ++c2)
            qf[c2] = *reinterpret_cast<const bf16x8*>(Qh + (size_t)qrow*HS + c2*32 + g*8);
    }

    f32x4 o[8];
    #pragma unroll
    for (int c = 0; c < 8; ++c) o[c] = (f32x4){0.f,0.f,0.f,0.f};
    float mrun[4], lrun[4];
    #pragma unroll
    for (int r = 0; r < 4; ++r) { mrun[r] = -1e30f; lrun[r] = 0.f; }

    for (int kv0 = 0; kv0 < q0 + 16; kv0 += 32) {
        // S = Q K^T : two 16x16 column tiles
        f32x4 s[2];
        s[0] = (f32x4){0.f,0.f,0.f,0.f};
        s[1] = (f32x4){0.f,0.f,0.f,0.f};
        #pragma unroll
        for (int h2 = 0; h2 < 2; ++h2) {
            int krow = kv0 + h2*16 + fr;
            if (krow > TT-1) krow = TT-1;
            #pragma unroll
            for (int c2 = 0; c2 < 4; ++c2) {
                bf16x8 kf = *reinterpret_cast<const bf16x8*>(Kh + (size_t)krow*HS + c2*32 + g*8);
                s[h2] = __builtin_amdgcn_mfma_f32_16x16x32_bf16(qf[c2], kf, s[h2], 0, 0, 0);
            }
        }
        // causal mask (only possible on the trailing tile)
        if (kv0 + 31 > q0) {
            #pragma unroll
            for (int h2 = 0; h2 < 2; ++h2)
                #pragma unroll
                for (int r = 0; r < 4; ++r) {
                    int col  = kv0 + h2*16 + fr;
                    int rowq = q0 + g*4 + r;
                    if (col > rowq) s[h2][r] = -1e30f;
                }
        }
        // online softmax: rows live in 16-lane groups
        float pm[4];
        #pragma unroll
        for (int r = 0; r < 4; ++r) pm[r] = fmaxf(s[0][r], s[1][r]);
        #pragma unroll
        for (int off = 1; off < 16; off <<= 1)
            #pragma unroll
            for (int r = 0; r < 4; ++r) pm[r] = fmaxf(pm[r], __shfl_xor(pm[r], off));
        float al[4], ps[4];
        #pragma unroll
        for (int r = 0; r < 4; ++r) {
            float mn = fmaxf(mrun[r], pm[r]);
            al[r] = __expf(mrun[r] - mn);
            mrun[r] = mn;
            ps[r] = 0.f;
        }
        #pragma unroll
        for (int h2 = 0; h2 < 2; ++h2)
            #pragma unroll
            for (int r = 0; r < 4; ++r) {
                float p = __expf(s[h2][r] - mrun[r]);
                s[h2][r] = p;
                ps[r] += p;
            }
        #pragma unroll
        for (int off = 1; off < 16; off <<= 1)
            #pragma unroll
            for (int r = 0; r < 4; ++r) ps[r] += __shfl_xor(ps[r], off);
        #pragma unroll
        for (int r = 0; r < 4; ++r) lrun[r] = lrun[r]*al[r] + ps[r];
        #pragma unroll
        for (int c = 0; c < 8; ++c)
            #pragma unroll
            for (int r = 0; r < 4; ++r) o[c][r] *= al[r];

        // P (16q x 32kv) -> LDS bf16, swizzled; then reread as MFMA A-fragment
        #pragma unroll
        for (int h2 = 0; h2 < 2; ++h2)
            #pragma unroll
            for (int r = 0; r < 4; ++r) {
                int prow  = g*4 + r;
                int pcolb = (h2*16 + fr) * 2;
                int addr  = prow*64 + (pcolb ^ ((prow & 3) << 4));
                *reinterpret_cast<short*>(reinterpret_cast<char*>(pl) + addr) = f2bf(s[h2][r]);
            }
        bf16x8 pa;
        {
            int arow = fr;
            int kb   = g*16;
            pa = *reinterpret_cast<const bf16x8*>(
                reinterpret_cast<const char*>(pl) + arow*64 + (kb ^ ((arow & 3) << 4)));
        }
        // O += P * V
        #pragma unroll
        for (int c = 0; c < 8; ++c) {
            bf16x8 vf;
            #pragma unroll
            for (int jj = 0; jj < 8; ++jj) {
                int kr = kv0 + g*8 + jj;
                if (kr > TT-1) kr = TT-1;
                vf[jj] = Vh[(size_t)kr*HS + c*16 + fr];
            }
            o[c] = __builtin_amdgcn_mfma_f32_16x16x32_bf16(pa, vf, o[c], 0, 0, 0);
        }
    }

    // epilogue: O[b, t, h*hs + d] bf16
    int b = bh >> 4, h = bh & 15;
    #pragma unroll
    for (int r = 0; r < 4; ++r) {
        int t = q0 + g*4 + r;
        float inv = 1.f / lrun[r];
        size_t base = ((size_t)(b*TT + t))*CC + (size_t)h*HS;
        #pragma unroll
        for (int c = 0; c < 8; ++c)
            O[base + c*16 + fr] = f2bf(o[c][r] * inv);
    }
}

extern "C" void kernel_launch(void* const* d_in, const int* in_sizes, int n_in,
                              void* d_out, int out_size, void* d_ws, size_t ws_size,
                              hipStream_t stream)
{
    const float* idx = (const float*)d_in[0];
    const float* Wq  = (const float*)d_in[1];
    const float* bq  = (const float*)d_in[2];
    const float* Wk  = (const float*)d_in[3];
    const float* bk  = (const float*)d_in[4];
    const float* Wv  = (const float*)d_in[5];
    const float* bv  = (const float*)d_in[6];
    const float* Wo  = (const float*)d_in[7];
    const float* bo  = (const float*)d_in[8];
    float* out = (float*)d_out;

    short* Xbf = (short*)d_ws;
    short* Wtq = Xbf + (size_t)MM*CC;
    short* Wtk = Wtq + (size_t)CC*CC;
    short* Wtv = Wtk + (size_t)CC*CC;
    short* Wto = Wtv + (size_t)CC*CC;
    short* Qb  = Wto + (size_t)CC*CC;
    short* Kb  = Qb  + (size_t)MM*CC;
    short* Vb  = Kb  + (size_t)MM*CC;
    short* Ob  = Vb  + (size_t)MM*CC;

    cvt_bf16_kernel<<<1024, 256, 0, stream>>>(idx, Xbf, MM*CC);
    wt_kernel<<<dim3(CC/32, CC/32, 4), dim3(32, 8), 0, stream>>>(
        Wq, Wk, Wv, Wo, Wtq, Wtk, Wtv, Wto);

    const float qs = 0.08838834764831845f;  // 1/sqrt(128)
    gemm_bt_kernel<0><<<dim3(MM/128, CC/128), 256, 0, stream>>>(Xbf, Wtq, bq, Qb, qs);
    gemm_bt_kernel<0><<<dim3(MM/128, CC/128), 256, 0, stream>>>(Xbf, Wtk, bk, Kb, 1.0f);
    gemm_bt_kernel<0><<<dim3(MM/128, CC/128), 256, 0, stream>>>(Xbf, Wtv, bv, Vb, 1.0f);

    attn_kernel<<<dim3(TT/64, BB*HH), 256, 0, stream>>>(Qb, Kb, Vb, Ob);

    gemm_bt_kernel<1><<<dim3(MM/128, CC/128), 256, 0, stream>>>(Ob, Wto, bo, out, 1.0f);
}

// Round 2
// 607.446 us; speedup vs baseline: 1.0243x; 1.0243x over previous
//
#include <hip/hip_runtime.h>
#include <hip/hip_bf16.h>

#define TT 2048
#define CC 2048
#define HH 16
#define HS 128
#define BB 2
#define MM (BB*TT)   // 4096

typedef __attribute__((ext_vector_type(8))) short bf16x8;
typedef __attribute__((ext_vector_type(4))) short bf16x4;
typedef __attribute__((ext_vector_type(4))) float f32x4;

__device__ __forceinline__ short f2bf(float x) {
    unsigned u = __float_as_uint(x);
    unsigned r = (u + 0x7FFFu + ((u >> 16) & 1u)) >> 16;
    return (short)r;
}

// ---------------- fp32 -> bf16 convert (idx) ----------------
__global__ void cvt_bf16_kernel(const float* __restrict__ x, short* __restrict__ y, int n) {
    int stride = gridDim.x * blockDim.x;
    for (int i = blockIdx.x * blockDim.x + threadIdx.x; i < n/4; i += stride) {
        float4 v = reinterpret_cast<const float4*>(x)[i];
        bf16x4 s;
        s[0] = f2bf(v.x); s[1] = f2bf(v.y); s[2] = f2bf(v.z); s[3] = f2bf(v.w);
        reinterpret_cast<bf16x4*>(y)[i] = s;
    }
}

// ---------------- W [k][n] fp32  ->  Wt [n][k] bf16 ----------------
__global__ void wt_kernel(const float* __restrict__ w0, const float* __restrict__ w1,
                          const float* __restrict__ w2, const float* __restrict__ w3,
                          short* __restrict__ o0, short* __restrict__ o1,
                          short* __restrict__ o2, short* __restrict__ o3)
{
    const float* W; short* Wt;
    switch (blockIdx.z) {
        case 0:  W = w0; Wt = o0; break;
        case 1:  W = w1; Wt = o1; break;
        case 2:  W = w2; Wt = o2; break;
        default: W = w3; Wt = o3; break;
    }
    __shared__ float tile[32][33];
    int tx = threadIdx.x, ty = threadIdx.y;           // block (32,8)
    int k0 = blockIdx.x * 32, n0 = blockIdx.y * 32;
    #pragma unroll
    for (int i = 0; i < 4; ++i)
        tile[ty + i*8][tx] = W[(size_t)(k0 + ty + i*8) * CC + n0 + tx];
    __syncthreads();
    #pragma unroll
    for (int i = 0; i < 4; ++i)
        Wt[(size_t)(n0 + ty + i*8) * CC + k0 + tx] = f2bf(tile[tx][ty + i*8]);
}

// ---------------- GEMM: C[M][N] = A[M][K] * Bt[N][K]^T (+bias, *scale) ----------------
// MODE 0: dst = bf16 [B,H,T,hs] (Q/K);  MODE 1: dst = fp32 [M][N];  MODE 2: dst = bf16 [B,H,hs,T] (V transposed)
template<int MODE>
__launch_bounds__(256)
__global__ void gemm_bt_kernel(const short* __restrict__ A, const short* __restrict__ Bt,
                               const float* __restrict__ bias, void* __restrict__ dst,
                               float scale)
{
    __shared__ __align__(16) short As[128*64];
    __shared__ __align__(16) short Bs[128*64];
    const int tid = threadIdx.x;
    const int lane = tid & 63;
    const int g = lane >> 4, fr = lane & 15;
    const int wid = tid >> 6;
    const int wr = wid >> 1, wc = wid & 1;
    const int m0 = blockIdx.x * 128, n0 = blockIdx.y * 128;

    f32x4 acc[4][4];
    #pragma unroll
    for (int i = 0; i < 4; ++i)
        #pragma unroll
        for (int j = 0; j < 4; ++j) acc[i][j] = (f32x4){0.f,0.f,0.f,0.f};

    for (int k0 = 0; k0 < CC; k0 += 64) {
        __syncthreads();
        #pragma unroll
        for (int i = 0; i < 4; ++i) {
            int c = i*256 + tid;
            int row = c >> 3;
            int kb  = (c & 7) * 16;                 // physical kbyte in LDS row (128B rows)
            int kbl = kb ^ ((row & 7) << 4);        // logical kbyte in global
            const bf16x8* src = reinterpret_cast<const bf16x8*>(
                reinterpret_cast<const char*>(A) + ((size_t)(m0+row)*CC + k0)*2 + kbl);
            *reinterpret_cast<bf16x8*>(reinterpret_cast<char*>(As) + row*128 + kb) = *src;
        }
        #pragma unroll
        for (int i = 0; i < 4; ++i) {
            int c = i*256 + tid;
            int row = c >> 3;
            int kb  = (c & 7) * 16;
            int kbl = kb ^ ((row & 7) << 4);
            const bf16x8* src = reinterpret_cast<const bf16x8*>(
                reinterpret_cast<const char*>(Bt) + ((size_t)(n0+row)*CC + k0)*2 + kbl);
            *reinterpret_cast<bf16x8*>(reinterpret_cast<char*>(Bs) + row*128 + kb) = *src;
        }
        __syncthreads();
        #pragma unroll
        for (int cch = 0; cch < 2; ++cch) {
            bf16x8 a[4], b[4];
            #pragma unroll
            for (int i = 0; i < 4; ++i) {
                int row = wr*64 + i*16 + fr;
                int kb  = cch*64 + g*16;
                int kph = kb ^ ((row & 7) << 4);
                a[i] = *reinterpret_cast<const bf16x8*>(
                    reinterpret_cast<const char*>(As) + row*128 + kph);
            }
            #pragma unroll
            for (int j = 0; j < 4; ++j) {
                int row = wc*64 + j*16 + fr;
                int kb  = cch*64 + g*16;
                int kph = kb ^ ((row & 7) << 4);
                b[j] = *reinterpret_cast<const bf16x8*>(
                    reinterpret_cast<const char*>(Bs) + row*128 + kph);
            }
            #pragma unroll
            for (int i = 0; i < 4; ++i)
                #pragma unroll
                for (int j = 0; j < 4; ++j)
                    acc[i][j] = __builtin_amdgcn_mfma_f32_16x16x32_bf16(a[i], b[j], acc[i][j], 0, 0, 0);
        }
    }

    // epilogue: C/D layout col=lane&15, row=(lane>>4)*4+reg
    #pragma unroll
    for (int j = 0; j < 4; ++j) {
        int n = n0 + wc*64 + j*16 + fr;
        float bv = bias[n];
        #pragma unroll
        for (int i = 0; i < 4; ++i) {
            #pragma unroll
            for (int r = 0; r < 4; ++r) {
                int m = m0 + wr*64 + i*16 + g*4 + r;
                float val = (acc[i][j][r] + bv) * scale;
                if (MODE == 0) {
                    int bb = m >> 11, t = m & (TT-1);
                    int h  = n >> 7,  d = n & (HS-1);
                    reinterpret_cast<short*>(dst)[((size_t)(bb*HH + h)*TT + t)*HS + d] = f2bf(val);
                } else if (MODE == 2) {
                    int bb = m >> 11, t = m & (TT-1);
                    int h  = n >> 7,  d = n & (HS-1);
                    reinterpret_cast<short*>(dst)[((size_t)(bb*HH + h)*HS + d)*TT + t] = f2bf(val);
                } else {
                    reinterpret_cast<float*>(dst)[(size_t)m*CC + n] = val;
                }
            }
        }
    }
}

// ---------------- causal flash attention v2 ----------------
// grid (16, B*H), block 256: wave w handles qtile (63 - (bx*4+w)), 32 q rows, kv-step 64
__launch_bounds__(256)
__global__ void attn_kernel(const short* __restrict__ Q, const short* __restrict__ K,
                            const short* __restrict__ Vt, short* __restrict__ O)
{
    const int tid = threadIdx.x;
    const int lane = tid & 63;
    const int wid = tid >> 6;
    const int g = lane >> 4, fr = lane & 15;
    const int bh = blockIdx.y;
    const int qidx = 63 - (blockIdx.x * 4 + wid);   // big tiles first
    const int q0 = qidx * 32;
    const short* Qh  = Q  + (size_t)bh * TT * HS;
    const short* Kh  = K  + (size_t)bh * TT * HS;
    const short* Vth = Vt + (size_t)bh * HS * TT;

    __shared__ __align__(16) short plds[4][32*64];
    char* pl = reinterpret_cast<char*>(plds[wid]);

    // Q fragments (Q was pre-scaled by log2(e)/sqrt(hs) in the QKV GEMM epilogue)
    bf16x8 qf[2][4];
    #pragma unroll
    for (int qt = 0; qt < 2; ++qt)
        #pragma unroll
        for (int c2 = 0; c2 < 4; ++c2)
            qf[qt][c2] = *reinterpret_cast<const bf16x8*>(
                Qh + (size_t)(q0 + qt*16 + fr)*HS + c2*32 + g*8);

    f32x4 o[2][8];
    #pragma unroll
    for (int qt = 0; qt < 2; ++qt)
        #pragma unroll
        for (int c = 0; c < 8; ++c) o[qt][c] = (f32x4){0.f,0.f,0.f,0.f};
    float mrun[2][4], lrun[2][4];
    #pragma unroll
    for (int qt = 0; qt < 2; ++qt)
        #pragma unroll
        for (int r = 0; r < 4; ++r) { mrun[qt][r] = -1e30f; lrun[qt][r] = 0.f; }

    for (int kv0 = 0; kv0 < q0 + 32; kv0 += 64) {
        // ---- S = Q K^T : 2 q-subtiles x 4 kv col-tiles (exp2 domain) ----
        f32x4 s[2][4];
        #pragma unroll
        for (int qt = 0; qt < 2; ++qt)
            #pragma unroll
            for (int h = 0; h < 4; ++h) s[qt][h] = (f32x4){0.f,0.f,0.f,0.f};
        #pragma unroll
        for (int h = 0; h < 4; ++h) {
            const short* kr = Kh + (size_t)(kv0 + h*16 + fr)*HS + g*8;
            #pragma unroll
            for (int c2 = 0; c2 < 4; ++c2) {
                bf16x8 kf = *reinterpret_cast<const bf16x8*>(kr + c2*32);
                s[0][h] = __builtin_amdgcn_mfma_f32_16x16x32_bf16(qf[0][c2], kf, s[0][h], 0, 0, 0);
                s[1][h] = __builtin_amdgcn_mfma_f32_16x16x32_bf16(qf[1][c2], kf, s[1][h], 0, 0, 0);
            }
        }
        // causal mask (only near the diagonal)
        if (kv0 + 63 > q0) {
            #pragma unroll
            for (int qt = 0; qt < 2; ++qt)
                #pragma unroll
                for (int h = 0; h < 4; ++h)
                    #pragma unroll
                    for (int r = 0; r < 4; ++r) {
                        int col = kv0 + h*16 + fr;
                        int row = q0 + qt*16 + g*4 + r;
                        if (col > row) s[qt][h][r] = -1e30f;
                    }
        }
        // ---- online softmax; only max needs cross-lane; l kept lane-partial ----
        #pragma unroll
        for (int qt = 0; qt < 2; ++qt) {
            float pm[4], al[4];
            #pragma unroll
            for (int r = 0; r < 4; ++r)
                pm[r] = fmaxf(fmaxf(s[qt][0][r], s[qt][1][r]), fmaxf(s[qt][2][r], s[qt][3][r]));
            #pragma unroll
            for (int off = 1; off < 16; off <<= 1)
                #pragma unroll
                for (int r = 0; r < 4; ++r) pm[r] = fmaxf(pm[r], __shfl_xor(pm[r], off));
            #pragma unroll
            for (int r = 0; r < 4; ++r) {
                float mn = fmaxf(mrun[qt][r], pm[r]);
                al[r] = exp2f(mrun[qt][r] - mn);
                mrun[qt][r] = mn;
                lrun[qt][r] *= al[r];
            }
            #pragma unroll
            for (int h = 0; h < 4; ++h)
                #pragma unroll
                for (int r = 0; r < 4; ++r) {
                    float p = exp2f(s[qt][h][r] - mrun[qt][r]);
                    s[qt][h][r] = p;
                    lrun[qt][r] += p;
                }
            #pragma unroll
            for (int c = 0; c < 8; ++c)
                #pragma unroll
                for (int r = 0; r < 4; ++r) o[qt][c][r] *= al[r];
            // P -> LDS bf16 (swizzled rows of 128B)
            #pragma unroll
            for (int h = 0; h < 4; ++h)
                #pragma unroll
                for (int r = 0; r < 4; ++r) {
                    int prow = qt*16 + g*4 + r;
                    int cb   = (h*16 + fr)*2;
                    *reinterpret_cast<short*>(pl + prow*128 + (cb ^ ((prow & 7) << 4))) =
                        f2bf(s[qt][h][r]);
                }
        }
        // ---- O += P * V  (V from transposed layout, contiguous 16B loads) ----
        #pragma unroll
        for (int kb = 0; kb < 2; ++kb) {
            bf16x8 pa[2];
            #pragma unroll
            for (int qt = 0; qt < 2; ++qt) {
                int row = qt*16 + fr;
                int cb  = kb*64 + g*16;
                pa[qt] = *reinterpret_cast<const bf16x8*>(pl + row*128 + (cb ^ ((row & 7) << 4)));
            }
            #pragma unroll
            for (int c = 0; c < 8; ++c) {
                bf16x8 vf = *reinterpret_cast<const bf16x8*>(
                    Vth + (size_t)(c*16 + fr)*TT + kv0 + kb*32 + g*8);
                o[0][c] = __builtin_amdgcn_mfma_f32_16x16x32_bf16(pa[0], vf, o[0][c], 0, 0, 0);
                o[1][c] = __builtin_amdgcn_mfma_f32_16x16x32_bf16(pa[1], vf, o[1][c], 0, 0, 0);
            }
        }
    }

    // final: reduce lane-partial l across the 16-lane group, normalize, store
    #pragma unroll
    for (int qt = 0; qt < 2; ++qt)
        #pragma unroll
        for (int off = 1; off < 16; off <<= 1)
            #pragma unroll
            for (int r = 0; r < 4; ++r) lrun[qt][r] += __shfl_xor(lrun[qt][r], off);

    int b = bh >> 4, h = bh & 15;
    #pragma unroll
    for (int qt = 0; qt < 2; ++qt)
        #pragma unroll
        for (int r = 0; r < 4; ++r) {
            int t = q0 + qt*16 + g*4 + r;
            float inv = 1.f / lrun[qt][r];
            size_t base = ((size_t)(b*TT + t))*CC + (size_t)h*HS;
            #pragma unroll
            for (int c = 0; c < 8; ++c)
                O[base + c*16 + fr] = f2bf(o[qt][c][r] * inv);
        }
}

extern "C" void kernel_launch(void* const* d_in, const int* in_sizes, int n_in,
                              void* d_out, int out_size, void* d_ws, size_t ws_size,
                              hipStream_t stream)
{
    const float* idx = (const float*)d_in[0];
    const float* Wq  = (const float*)d_in[1];
    const float* bq  = (const float*)d_in[2];
    const float* Wk  = (const float*)d_in[3];
    const float* bk  = (const float*)d_in[4];
    const float* Wv  = (const float*)d_in[5];
    const float* bv  = (const float*)d_in[6];
    const float* Wo  = (const float*)d_in[7];
    const float* bo  = (const float*)d_in[8];
    float* out = (float*)d_out;

    short* Xbf = (short*)d_ws;
    short* Wtq = Xbf + (size_t)MM*CC;
    short* Wtk = Wtq + (size_t)CC*CC;
    short* Wtv = Wtk + (size_t)CC*CC;
    short* Wto = Wtv + (size_t)CC*CC;
    short* Qb  = Wto + (size_t)CC*CC;
    short* Kb  = Qb  + (size_t)MM*CC;
    short* Vtb = Kb  + (size_t)MM*CC;
    short* Ob  = Vtb + (size_t)MM*CC;

    cvt_bf16_kernel<<<1024, 256, 0, stream>>>(idx, Xbf, MM*CC);
    wt_kernel<<<dim3(CC/32, CC/32, 4), dim3(32, 8), 0, stream>>>(
        Wq, Wk, Wv, Wo, Wtq, Wtk, Wtv, Wto);

    const float qs = 0.08838834764831845f * 1.4426950408889634f;  // log2(e)/sqrt(128)
    gemm_bt_kernel<0><<<dim3(MM/128, CC/128), 256, 0, stream>>>(Xbf, Wtq, bq, Qb, qs);
    gemm_bt_kernel<0><<<dim3(MM/128, CC/128), 256, 0, stream>>>(Xbf, Wtk, bk, Kb, 1.0f);
    gemm_bt_kernel<2><<<dim3(MM/128, CC/128), 256, 0, stream>>>(Xbf, Wtv, bv, Vtb, 1.0f);

    attn_kernel<<<dim3(16, BB*HH), 256, 0, stream>>>(Qb, Kb, Vtb, Ob);

    gemm_bt_kernel<1><<<dim3(MM/128, CC/128), 256, 0, stream>>>(Ob, Wto, bo, out, 1.0f);
}

// Round 3
// 499.315 us; speedup vs baseline: 1.2461x; 1.2166x over previous
//
#include <hip/hip_runtime.h>
#include <hip/hip_bf16.h>

#define TT 2048
#define CC 2048
#define HH 16
#define HS 128
#define BB 2
#define MM (BB*TT)   // 4096

typedef __attribute__((ext_vector_type(8))) short bf16x8;
typedef __attribute__((ext_vector_type(4))) short bf16x4;
typedef __attribute__((ext_vector_type(4))) float f32x4;

__device__ __forceinline__ short f2bf(float x) {
    unsigned u = __float_as_uint(x);
    unsigned r = (u + 0x7FFFu + ((u >> 16) & 1u)) >> 16;
    return (short)r;
}

// ---------------- fp32 -> bf16 convert (idx) ----------------
__global__ void cvt_bf16_kernel(const float* __restrict__ x, short* __restrict__ y, int n) {
    int stride = gridDim.x * blockDim.x;
    for (int i = blockIdx.x * blockDim.x + threadIdx.x; i < n/4; i += stride) {
        float4 v = reinterpret_cast<const float4*>(x)[i];
        bf16x4 s;
        s[0] = f2bf(v.x); s[1] = f2bf(v.y); s[2] = f2bf(v.z); s[3] = f2bf(v.w);
        reinterpret_cast<bf16x4*>(y)[i] = s;
    }
}

// ---------------- W [k][n] fp32  ->  Wt [n][k] bf16 ----------------
__global__ void wt_kernel(const float* __restrict__ w0, const float* __restrict__ w1,
                          const float* __restrict__ w2, const float* __restrict__ w3,
                          short* __restrict__ o0, short* __restrict__ o1,
                          short* __restrict__ o2, short* __restrict__ o3)
{
    const float* W; short* Wt;
    switch (blockIdx.z) {
        case 0:  W = w0; Wt = o0; break;
        case 1:  W = w1; Wt = o1; break;
        case 2:  W = w2; Wt = o2; break;
        default: W = w3; Wt = o3; break;
    }
    __shared__ float tile[32][33];
    int tx = threadIdx.x, ty = threadIdx.y;           // block (32,8)
    int k0 = blockIdx.x * 32, n0 = blockIdx.y * 32;
    #pragma unroll
    for (int i = 0; i < 4; ++i)
        tile[ty + i*8][tx] = W[(size_t)(k0 + ty + i*8) * CC + n0 + tx];
    __syncthreads();
    #pragma unroll
    for (int i = 0; i < 4; ++i)
        Wt[(size_t)(n0 + ty + i*8) * CC + k0 + tx] = f2bf(tile[tx][ty + i*8]);
}

// ---------------- GEMM: C[M][N] = A[M][K] * Bt[N][K]^T (+bias, *scale) ----------------
// MODE 0: dst = bf16 [B,H,T,hs] (Q/K);  MODE 1: dst = fp32 [M][N];  MODE 2: dst = bf16 [B,H,hs,T] (V transposed)
template<int MODE>
__launch_bounds__(256)
__global__ void gemm_bt_kernel(const short* __restrict__ A, const short* __restrict__ Bt,
                               const float* __restrict__ bias, void* __restrict__ dst,
                               float scale)
{
    __shared__ __align__(16) short As[128*64];
    __shared__ __align__(16) short Bs[128*64];
    const int tid = threadIdx.x;
    const int lane = tid & 63;
    const int g = lane >> 4, fr = lane & 15;
    const int wid = tid >> 6;
    const int wr = wid >> 1, wc = wid & 1;
    const int m0 = blockIdx.x * 128, n0 = blockIdx.y * 128;

    f32x4 acc[4][4];
    #pragma unroll
    for (int i = 0; i < 4; ++i)
        #pragma unroll
        for (int j = 0; j < 4; ++j) acc[i][j] = (f32x4){0.f,0.f,0.f,0.f};

    for (int k0 = 0; k0 < CC; k0 += 64) {
        __syncthreads();
        #pragma unroll
        for (int i = 0; i < 4; ++i) {
            int c = i*256 + tid;
            int row = c >> 3;
            int kb  = (c & 7) * 16;                 // physical kbyte in LDS row (128B rows)
            int kbl = kb ^ ((row & 7) << 4);        // logical kbyte in global
            const bf16x8* src = reinterpret_cast<const bf16x8*>(
                reinterpret_cast<const char*>(A) + ((size_t)(m0+row)*CC + k0)*2 + kbl);
            *reinterpret_cast<bf16x8*>(reinterpret_cast<char*>(As) + row*128 + kb) = *src;
        }
        #pragma unroll
        for (int i = 0; i < 4; ++i) {
            int c = i*256 + tid;
            int row = c >> 3;
            int kb  = (c & 7) * 16;
            int kbl = kb ^ ((row & 7) << 4);
            const bf16x8* src = reinterpret_cast<const bf16x8*>(
                reinterpret_cast<const char*>(Bt) + ((size_t)(n0+row)*CC + k0)*2 + kbl);
            *reinterpret_cast<bf16x8*>(reinterpret_cast<char*>(Bs) + row*128 + kb) = *src;
        }
        __syncthreads();
        #pragma unroll
        for (int cch = 0; cch < 2; ++cch) {
            bf16x8 a[4], b[4];
            #pragma unroll
            for (int i = 0; i < 4; ++i) {
                int row = wr*64 + i*16 + fr;
                int kb  = cch*64 + g*16;
                int kph = kb ^ ((row & 7) << 4);
                a[i] = *reinterpret_cast<const bf16x8*>(
                    reinterpret_cast<const char*>(As) + row*128 + kph);
            }
            #pragma unroll
            for (int j = 0; j < 4; ++j) {
                int row = wc*64 + j*16 + fr;
                int kb  = cch*64 + g*16;
                int kph = kb ^ ((row & 7) << 4);
                b[j] = *reinterpret_cast<const bf16x8*>(
                    reinterpret_cast<const char*>(Bs) + row*128 + kph);
            }
            #pragma unroll
            for (int i = 0; i < 4; ++i)
                #pragma unroll
                for (int j = 0; j < 4; ++j)
                    acc[i][j] = __builtin_amdgcn_mfma_f32_16x16x32_bf16(a[i], b[j], acc[i][j], 0, 0, 0);
        }
    }

    // epilogue: C/D layout col=lane&15, row=(lane>>4)*4+reg
    #pragma unroll
    for (int j = 0; j < 4; ++j) {
        int n = n0 + wc*64 + j*16 + fr;
        float bv = bias[n];
        #pragma unroll
        for (int i = 0; i < 4; ++i) {
            #pragma unroll
            for (int r = 0; r < 4; ++r) {
                int m = m0 + wr*64 + i*16 + g*4 + r;
                float val = (acc[i][j][r] + bv) * scale;
                if (MODE == 0) {
                    int bb = m >> 11, t = m & (TT-1);
                    int h  = n >> 7,  d = n & (HS-1);
                    reinterpret_cast<short*>(dst)[((size_t)(bb*HH + h)*TT + t)*HS + d] = f2bf(val);
                } else if (MODE == 2) {
                    int bb = m >> 11, t = m & (TT-1);
                    int h  = n >> 7,  d = n & (HS-1);
                    reinterpret_cast<short*>(dst)[((size_t)(bb*HH + h)*HS + d)*TT + t] = f2bf(val);
                } else {
                    reinterpret_cast<float*>(dst)[(size_t)m*CC + n] = val;
                }
            }
        }
    }
}

// ---------------- causal flash attention v3: block-cooperative LDS staging ----------------
// grid 512 blocks x 256 threads. Block: 128 q rows (4 waves x 32), kv-step 64.
// K tile [64][128]b16 + Vt tile [128][64]b16 double-buffered in LDS, XOR-swizzled.
__launch_bounds__(256, 2)
__global__ void attn_kernel(const short* __restrict__ Q, const short* __restrict__ K,
                            const short* __restrict__ Vt, short* __restrict__ O)
{
    __shared__ __align__(16) short Ks[2][64*128];   // 2 x 16KB
    __shared__ __align__(16) short Vs[2][128*64];   // 2 x 16KB
    __shared__ __align__(16) short Ps[4][32*64];    // 16KB (per-wave P)

    const int tid = threadIdx.x;
    const int lane = tid & 63;
    const int wid = tid >> 6;
    const int g = lane >> 4, fr = lane & 15;

    // remap so each XCD (~ blockIdx%8) serves only 4 heads -> 4MB KV set ~ L2
    const int dd = blockIdx.x;          // 0..511
    const int g8 = dd & 7;
    const int i0 = dd >> 3;             // 0..63
    const int bh = g8*4 + (i0 >> 4);    // head 0..31
    const int qb = 15 - (i0 & 15);      // heavy-first (harmless)
    const int q0 = qb * 128;
    const int wq0 = q0 + wid*32;        // this wave's 32 q rows

    const short* Qh = Q + (size_t)bh * TT * HS;
    const char*  Kg = (const char*)(K  + (size_t)bh * TT * HS);
    const char*  Vg = (const char*)(Vt + (size_t)bh * HS * TT);

    // Q fragments (Q pre-scaled by log2(e)/sqrt(hs))
    bf16x8 qf[2][4];
    #pragma unroll
    for (int qt = 0; qt < 2; ++qt)
        #pragma unroll
        for (int c2 = 0; c2 < 4; ++c2)
            qf[qt][c2] = *reinterpret_cast<const bf16x8*>(
                Qh + (size_t)(wq0 + qt*16 + fr)*HS + c2*32 + g*8);

    f32x4 o[2][8];
    #pragma unroll
    for (int qt = 0; qt < 2; ++qt)
        #pragma unroll
        for (int c = 0; c < 8; ++c) o[qt][c] = (f32x4){0.f,0.f,0.f,0.f};
    float mrun[2][4], lrun[2][4];
    #pragma unroll
    for (int qt = 0; qt < 2; ++qt)
        #pragma unroll
        for (int r = 0; r < 4; ++r) { mrun[qt][r] = -1e30f; lrun[qt][r] = 0.f; }

    bf16x8 kreg[4], vreg[4];
    auto stage_issue = [&](int kv0) {
        #pragma unroll
        for (int i = 0; i < 4; ++i) {                 // K tile: 64 rows x 256B
            int c = i*256 + tid;
            int row = c >> 4, kb = (c & 15) * 16;
            int kbl = kb ^ ((row & 7) << 4);
            kreg[i] = *reinterpret_cast<const bf16x8*>(Kg + (size_t)(kv0 + row)*256 + kbl);
        }
        #pragma unroll
        for (int i = 0; i < 4; ++i) {                 // Vt tile: 128 rows x 128B
            int c = i*256 + tid;
            int row = c >> 3, kb = (c & 7) * 16;
            int kbl = kb ^ ((row & 7) << 4);
            vreg[i] = *reinterpret_cast<const bf16x8*>(
                Vg + ((size_t)row*TT + kv0)*2 + kbl);
        }
    };
    auto stage_write = [&](int p) {
        char* Kd = reinterpret_cast<char*>(Ks[p]);
        char* Vd = reinterpret_cast<char*>(Vs[p]);
        #pragma unroll
        for (int i = 0; i < 4; ++i)
            *reinterpret_cast<bf16x8*>(Kd + (i*256 + tid)*16) = kreg[i];
        #pragma unroll
        for (int i = 0; i < 4; ++i)
            *reinterpret_cast<bf16x8*>(Vd + (i*256 + tid)*16) = vreg[i];
    };

    const int nst = q0/64 + 2;
    stage_issue(0);
    stage_write(0);
    int p = 0;
    char* pw = reinterpret_cast<char*>(Ps[wid]);

    for (int s2 = 0; s2 < nst; ++s2) {
        __syncthreads();                      // buf[p] ready; prev reads of buf[p^1] done
        const int kv0 = s2 * 64;
        if (s2 + 1 < nst) stage_issue(kv0 + 64);   // loads in flight across compute

        const char* Kl = reinterpret_cast<const char*>(Ks[p]);
        const char* Vl = reinterpret_cast<const char*>(Vs[p]);

        // ---- S = Q K^T ----
        f32x4 s[2][4];
        #pragma unroll
        for (int qt = 0; qt < 2; ++qt)
            #pragma unroll
            for (int h = 0; h < 4; ++h) s[qt][h] = (f32x4){0.f,0.f,0.f,0.f};
        #pragma unroll
        for (int h = 0; h < 4; ++h) {
            bf16x8 kf[4];
            int row = h*16 + fr;
            #pragma unroll
            for (int c2 = 0; c2 < 4; ++c2)
                kf[c2] = *reinterpret_cast<const bf16x8*>(
                    Kl + row*256 + ((c2*64 + g*16) ^ ((row & 7) << 4)));
            #pragma unroll
            for (int c2 = 0; c2 < 4; ++c2) {
                s[0][h] = __builtin_amdgcn_mfma_f32_16x16x32_bf16(qf[0][c2], kf[c2], s[0][h], 0, 0, 0);
                s[1][h] = __builtin_amdgcn_mfma_f32_16x16x32_bf16(qf[1][c2], kf[c2], s[1][h], 0, 0, 0);
            }
        }
        // causal mask
        if (kv0 + 63 > wq0) {
            #pragma unroll
            for (int qt = 0; qt < 2; ++qt)
                #pragma unroll
                for (int h = 0; h < 4; ++h)
                    #pragma unroll
                    for (int r = 0; r < 4; ++r) {
                        int col = kv0 + h*16 + fr;
                        int row = wq0 + qt*16 + g*4 + r;
                        if (col > row) s[qt][h][r] = -1e30f;
                    }
        }
        // ---- online softmax (exp2 domain; l lane-partial) ----
        #pragma unroll
        for (int qt = 0; qt < 2; ++qt) {
            float pm[4], al[4];
            #pragma unroll
            for (int r = 0; r < 4; ++r)
                pm[r] = fmaxf(fmaxf(s[qt][0][r], s[qt][1][r]), fmaxf(s[qt][2][r], s[qt][3][r]));
            #pragma unroll
            for (int off = 1; off < 16; off <<= 1)
                #pragma unroll
                for (int r = 0; r < 4; ++r) pm[r] = fmaxf(pm[r], __shfl_xor(pm[r], off));
            #pragma unroll
            for (int r = 0; r < 4; ++r) {
                float mn = fmaxf(mrun[qt][r], pm[r]);
                al[r] = exp2f(mrun[qt][r] - mn);
                mrun[qt][r] = mn;
                lrun[qt][r] *= al[r];
            }
            #pragma unroll
            for (int h = 0; h < 4; ++h)
                #pragma unroll
                for (int r = 0; r < 4; ++r) {
                    float pv = exp2f(s[qt][h][r] - mrun[qt][r]);
                    s[qt][h][r] = pv;
                    lrun[qt][r] += pv;
                }
            #pragma unroll
            for (int c = 0; c < 8; ++c)
                #pragma unroll
                for (int r = 0; r < 4; ++r) o[qt][c][r] *= al[r];
            // P -> per-wave LDS (swizzled 128B rows)
            #pragma unroll
            for (int h = 0; h < 4; ++h)
                #pragma unroll
                for (int r = 0; r < 4; ++r) {
                    int prow = qt*16 + g*4 + r;
                    int cb   = (h*16 + fr)*2;
                    *reinterpret_cast<short*>(pw + prow*128 + (cb ^ ((prow & 7) << 4))) =
                        f2bf(s[qt][h][r]);
                }
        }
        // ---- O += P * V (both from LDS) ----
        #pragma unroll
        for (int kb = 0; kb < 2; ++kb) {
            bf16x8 pa[2];
            #pragma unroll
            for (int qt = 0; qt < 2; ++qt) {
                int row = qt*16 + fr;
                pa[qt] = *reinterpret_cast<const bf16x8*>(
                    pw + row*128 + ((kb*64 + g*16) ^ ((row & 7) << 4)));
            }
            #pragma unroll
            for (int c = 0; c < 8; ++c) {
                int row = c*16 + fr;
                bf16x8 vf = *reinterpret_cast<const bf16x8*>(
                    Vl + row*128 + ((kb*64 + g*16) ^ ((row & 7) << 4)));
                o[0][c] = __builtin_amdgcn_mfma_f32_16x16x32_bf16(pa[0], vf, o[0][c], 0, 0, 0);
                o[1][c] = __builtin_amdgcn_mfma_f32_16x16x32_bf16(pa[1], vf, o[1][c], 0, 0, 0);
            }
        }
        if (s2 + 1 < nst) stage_write(p ^ 1);
        p ^= 1;
    }

    // final: reduce lane-partial l across 16-lane group, normalize, store
    #pragma unroll
    for (int qt = 0; qt < 2; ++qt)
        #pragma unroll
        for (int off = 1; off < 16; off <<= 1)
            #pragma unroll
            for (int r = 0; r < 4; ++r) lrun[qt][r] += __shfl_xor(lrun[qt][r], off);

    int b = bh >> 4, h = bh & 15;
    #pragma unroll
    for (int qt = 0; qt < 2; ++qt)
        #pragma unroll
        for (int r = 0; r < 4; ++r) {
            int t = wq0 + qt*16 + g*4 + r;
            float inv = 1.f / lrun[qt][r];
            size_t base = ((size_t)(b*TT + t))*CC + (size_t)h*HS;
            #pragma unroll
            for (int c = 0; c < 8; ++c)
                O[base + c*16 + fr] = f2bf(o[qt][c][r] * inv);
        }
}

extern "C" void kernel_launch(void* const* d_in, const int* in_sizes, int n_in,
                              void* d_out, int out_size, void* d_ws, size_t ws_size,
                              hipStream_t stream)
{
    const float* idx = (const float*)d_in[0];
    const float* Wq  = (const float*)d_in[1];
    const float* bq  = (const float*)d_in[2];
    const float* Wk  = (const float*)d_in[3];
    const float* bk  = (const float*)d_in[4];
    const float* Wv  = (const float*)d_in[5];
    const float* bv  = (const float*)d_in[6];
    const float* Wo  = (const float*)d_in[7];
    const float* bo  = (const float*)d_in[8];
    float* out = (float*)d_out;

    short* Xbf = (short*)d_ws;
    short* Wtq = Xbf + (size_t)MM*CC;
    short* Wtk = Wtq + (size_t)CC*CC;
    short* Wtv = Wtk + (size_t)CC*CC;
    short* Wto = Wtv + (size_t)CC*CC;
    short* Qb  = Wto + (size_t)CC*CC;
    short* Kb  = Qb  + (size_t)MM*CC;
    short* Vtb = Kb  + (size_t)MM*CC;
    short* Ob  = Vtb + (size_t)MM*CC;

    cvt_bf16_kernel<<<1024, 256, 0, stream>>>(idx, Xbf, MM*CC);
    wt_kernel<<<dim3(CC/32, CC/32, 4), dim3(32, 8), 0, stream>>>(
        Wq, Wk, Wv, Wo, Wtq, Wtk, Wtv, Wto);

    const float qs = 0.08838834764831845f * 1.4426950408889634f;  // log2(e)/sqrt(128)
    gemm_bt_kernel<0><<<dim3(MM/128, CC/128), 256, 0, stream>>>(Xbf, Wtq, bq, Qb, qs);
    gemm_bt_kernel<0><<<dim3(MM/128, CC/128), 256, 0, stream>>>(Xbf, Wtk, bk, Kb, 1.0f);
    gemm_bt_kernel<2><<<dim3(MM/128, CC/128), 256, 0, stream>>>(Xbf, Wtv, bv, Vtb, 1.0f);

    attn_kernel<<<dim3(512), 256, 0, stream>>>(Qb, Kb, Vtb, Ob);

    gemm_bt_kernel<1><<<dim3(MM/128, CC/128), 256, 0, stream>>>(Ob, Wto, bo, out, 1.0f);
}